// Round 1
// baseline (3884.708 us; speedup 1.0000x reference)
//
#include <hip/hip_runtime.h>

// ---------------------------------------------------------------------------
// RNN scan on MI355X — round 3.
// R redesign v3: 64 blocks x 512 threads, __launch_bounds__(512,2) so the
// compiler gets the full 256-reg budget (round-2 capped at 128 arch VGPRs and
// spilled ureg to AGPRs -> v_accvgpr_read per use).
//   Lane map: t = w*64 + l, kq = (t>>4)&3, cl = t&15.
//   Thread computes cols {w*64 + e*16 + cl : e=0..3} over its kq k-quarter
//   (64 pairs). kq-reduction is INTRA-WAVE via shfl_xor(16/32) -> no ptab,
//   ONE barrier per step (h double-buffered, quarter-padded vs bank conflict).
//   U split: 44 pair-slots in VGPRs, 12 in LDS (96 KB/step), 8 from global
//   (64 KB/step, L1/L2-resident) to engage the idle vector-memory pipe.
// ---------------------------------------------------------------------------

#define NRP 44            // pair-slots (uint4 of 4 cols) resident in VGPRs
#define NTL 12            // pair-slots resident in LDS
#define NTG 8             // pair-slots streamed from global (L1/L2)

typedef _Float16 h2_t __attribute__((ext_vector_type(2)));
union U32H2 { unsigned u; h2_t h; _Float16 f[2]; };

__device__ inline unsigned pkf16(float a, float b){
  U32H2 v; v.f[0] = (_Float16)a; v.f[1] = (_Float16)b; return v.u;
}

__device__ inline float dot2(unsigned a, unsigned b, float c){
  U32H2 x, y; x.u = a; y.u = b;
#if __has_builtin(__builtin_amdgcn_fdot2)
  return __builtin_amdgcn_fdot2(x.h, y.h, c, false);   // v_dot2_f32_f16
#else
  return c + (float)x.f[0]*(float)y.f[0] + (float)x.f[1]*(float)y.f[1];
#endif
}

#define DOT4(u, hx) \
  a0 = dot2((u).x, (hx), a0); a1 = dot2((u).y, (hx), a1); \
  a2 = dot2((u).z, (hx), a2); a3 = dot2((u).w, (hx), a3);

// ---------------------------------------------------------------------------
// P: pack weights. 256 blocks x 256 threads.
//  - Wp[kp*512+j] = pack(Ww[2kp][j], Ww[2kp+1][j])        (idx < 65536)
//  - U layout for scan thread t (w=t>>6, kq=(t>>4)&3, cl=t&15), slot j<64:
//      pair p = kq*64 + j, cols c_e = w*64 + e*16 + cl (e=0..3)
//      v = { pack(U[2p][c_e], U[2p+1][c_e]) }
//      j<NRP -> UrP[j*512+t]; j<NRP+NTL -> UtL[(j-NRP)*512+t];
//      else  -> UtG[(j-NRP-NTL)*512+t]
// ---------------------------------------------------------------------------
__global__ __launch_bounds__(256) void prep_pack(const float* __restrict__ Ww,
                                                 const float* __restrict__ Uw,
                                                 unsigned* __restrict__ Wp,
                                                 uint4* __restrict__ UrP,
                                                 uint4* __restrict__ UtL,
                                                 uint4* __restrict__ UtG){
  int idx = blockIdx.x*256 + threadIdx.x;
  { // W pack
    int kp = idx >> 9, j = idx & 511;
    Wp[idx] = pkf16(Ww[(2*kp)*512 + j], Ww[(2*kp+1)*512 + j]);
  }
  if (idx < 512*64){
    int t = idx & 511, j = idx >> 9;          // j = pair slot 0..63
    int w = t >> 6, kq = (t >> 4) & 3, cl = t & 15;
    int p = kq*64 + j, k0 = 2*p;
    uint4 v;
    unsigned* vv = (unsigned*)&v;
    #pragma unroll
    for (int e=0;e<4;e++){
      int c = w*64 + e*16 + cl;
      vv[e] = pkf16(Uw[k0*512 + c], Uw[(k0+1)*512 + c]);
    }
    if      (j < NRP)      UrP[j*512 + t] = v;
    else if (j < NRP+NTL)  UtL[(j-NRP)*512 + t] = v;
    else                   UtG[(j-NRP-NTL)*512 + t] = v;
  }
}

// ---------------------------------------------------------------------------
// G: wx GEMM. Output now plain f16: wxh[(b*2048+s)*512 + col].
// ---------------------------------------------------------------------------
__global__ __launch_bounds__(256) void gemm_wx(const float* __restrict__ x,
                                               const unsigned* __restrict__ Wp,
                                               const float* __restrict__ Wb,
                                               _Float16* __restrict__ wxh){
  __shared__ unsigned xt[32][128];      // 16 KB
  const int tid = threadIdx.x;
  const int b = blockIdx.x >> 6, sb = blockIdx.x & 63;
  const float* xrow = x + ((size_t)(b*2048 + sb*32))*256;
  #pragma unroll
  for (int i=0;i<8;i++){
    int f = i*256 + tid;
    int r = f >> 6, c4 = f & 63;
    float4 v = ((const float4*)xrow)[r*64 + c4];
    xt[r][2*c4]   = pkf16(v.x, v.y);
    xt[r][2*c4+1] = pkf16(v.z, v.w);
  }
  float acc0[32], acc1[32];
  #pragma unroll
  for (int r=0;r<32;r++){ acc0[r]=0.f; acc1[r]=0.f; }
  __syncthreads();
  #pragma unroll 4
  for (int kp=0;kp<128;kp++){
    unsigned w0 = Wp[kp*512 + tid];
    unsigned w1 = Wp[kp*512 + tid + 256];
    #pragma unroll
    for (int r=0;r<32;r++){
      unsigned xv = xt[r][kp];
      acc0[r] = dot2(xv, w0, acc0[r]);
      acc1[r] = dot2(xv, w1, acc1[r]);
    }
  }
  float wb0 = Wb[tid], wb1 = Wb[tid+256];
  _Float16* o = wxh + ((size_t)(b*2048 + sb*32))*512;
  #pragma unroll
  for (int r=0;r<32;r++){
    o[r*512 + tid]       = (_Float16)(acc0[r]+wb0);
    o[r*512 + 256 + tid] = (_Float16)(acc1[r]+wb1);
  }
}

// ---------------------------------------------------------------------------
// R: sequential scan. 64 blocks x 512 threads, 2 waves/SIMD, 256-reg budget.
// LDS: utail 96 KB + h dbuf 2176 B + rbuf = ~100.5 KB -> 1 block/CU.
// h buffer layout: quarter q at byte q*272 (256 B data + 16 B pad) so the
// 4 kq groups of a wave hit disjoint bank-quads on broadcast b128 reads.
// ---------------------------------------------------------------------------
__global__ __launch_bounds__(512, 2) void rnn_scan(const uint4* __restrict__ UrP,
                                                   const uint4* __restrict__ UtL,
                                                   const uint4* __restrict__ UtG,
                                                   const _Float16* __restrict__ wxh,
                                                   const float* __restrict__ Ub,
                                                   const float* __restrict__ Vw,
                                                   const float* __restrict__ Vb,
                                                   float* __restrict__ out){
  __shared__ uint4 utail[NTL*512];               // 96 KB
  __shared__ __align__(16) char hb[2*1088];      // 2 x (4 quarters x 272 B)
  __shared__ float rbuf[16];
  const int t  = threadIdx.x;
  const int b  = blockIdx.x;
  const int kq = (t >> 4) & 3;

  uint4 ureg[NRP];                               // 176 arch VGPRs
  #pragma unroll
  for (int j=0;j<NRP;j++) ureg[j] = UrP[j*512 + t];
  #pragma unroll
  for (int i=0;i<NTL;i++) utail[i*512 + t] = UtL[i*512 + t];
  for (int i=t;i<544;i+=512) ((unsigned*)hb)[i] = 0;   // zero both h buffers
  const float ub_c = Ub[t];                      // this thread's column = t
  const _Float16* wxb = wxh + (size_t)b*2048*512;
  _Float16 wc = wxb[t];                          // wx[t=0]
  _Float16 wn = wxb[512 + t];                    // wx[t=1]
  const uint4* hq0 = (const uint4*)(hb + kq*272);
  const uint4* hq1 = (const uint4*)(hb + 1088 + kq*272);
  _Float16* hw0 = (_Float16*)(hb +        (t>>7)*272) + (t&127);
  _Float16* hw1 = (_Float16*)(hb + 1088 + (t>>7)*272) + (t&127);
  const uint4* gt = UtG + t;                     // global tail base (opaque)
  float hf = 0.f;
  __syncthreads();

  #pragma unroll 1
  for (int ts=0; ts<2048; ts++){
    const uint4* hq = (ts&1) ? hq1 : hq0;        // read buffer
    _Float16*    hw = (ts&1) ? hw0 : hw1;        // write buffer (other one)

    // issue global tail loads early (constant data, L1/L2-resident)
    uint4 gA0 = gt[0*512], gA1 = gt[1*512], gA2 = gt[2*512], gA3 = gt[3*512];
    uint4 gB0 = gt[4*512], gB1 = gt[5*512], gB2 = gt[6*512], gB3 = gt[7*512];

    _Float16 wuse = wc; wc = wn;                 // wx prefetch rotate (2 ahead)
    int tn = (ts+2 < 2048) ? (ts+2) : 2047;
    wn = wxb[(size_t)tn*512 + t];

    float a0=0.f, a1=0.f, a2=0.f, a3=0.f;        // 4 columns (e=0..3)
    #pragma unroll
    for (int g=0; g<NRP/4; g++){                 // VGPR-resident slots 0..43
      uint4 hv = hq[g];
      uint4 u0 = ureg[4*g+0], u1 = ureg[4*g+1];
      uint4 u2 = ureg[4*g+2], u3 = ureg[4*g+3];
      DOT4(u0, hv.x); DOT4(u1, hv.y); DOT4(u2, hv.z); DOT4(u3, hv.w);
    }
    { // global batch A = slots 56..59 (h group 14); frees 16 regs early
      uint4 hv = hq[14];
      DOT4(gA0, hv.x); DOT4(gA1, hv.y); DOT4(gA2, hv.z); DOT4(gA3, hv.w);
    }
    #pragma unroll
    for (int i=0;i<NTL/4;i++){                   // LDS slots 44..55 (groups 11..13)
      uint4 hv = hq[11+i];
      uint4 u0 = utail[(4*i+0)*512+t], u1 = utail[(4*i+1)*512+t];
      uint4 u2 = utail[(4*i+2)*512+t], u3 = utail[(4*i+3)*512+t];
      DOT4(u0, hv.x); DOT4(u1, hv.y); DOT4(u2, hv.z); DOT4(u3, hv.w);
    }
    { // global batch B = slots 60..63 (h group 15)
      uint4 hv = hq[15];
      DOT4(gB0, hv.x); DOT4(gB1, hv.y); DOT4(gB2, hv.z); DOT4(gB3, hv.w);
    }

    // intra-wave kq reduction: lanes l, l^16, l^32, l^48 hold the 4 partials
    a0 += __shfl_xor(a0, 16); a0 += __shfl_xor(a0, 32);
    a1 += __shfl_xor(a1, 16); a1 += __shfl_xor(a1, 32);
    a2 += __shfl_xor(a2, 16); a2 += __shfl_xor(a2, 32);
    a3 += __shfl_xor(a3, 16); a3 += __shfl_xor(a3, 32);
    float s = (kq & 2) ? ((kq & 1) ? a3 : a2) : ((kq & 1) ? a1 : a0);
    float pre = s + (float)wuse + ub_c;
    hf = 1.f - 2.f/(__expf(2.f*pre) + 1.f);      // tanh, saturates cleanly
    *hw = (_Float16)hf;                          // write h_new[col t]
    __syncthreads();                             // ONE barrier per step
    asm volatile("" : "+v"(gt));                 // keep gv loads inside loop
  }

  // epilogue: out[b,:] = sigmoid(h_T @ V + Vb); thread t holds h_T[t]
  float p0 = hf*Vw[2*t], p1 = hf*Vw[2*t+1];
  #pragma unroll
  for (int off=32; off>0; off>>=1){
    p0 += __shfl_down(p0, off);
    p1 += __shfl_down(p1, off);
  }
  if ((t & 63) == 0){
    rbuf[(t>>6)*2]   = p0;
    rbuf[(t>>6)*2+1] = p1;
  }
  __syncthreads();
  if (t == 0){
    float s0 = Vb[0], s1 = Vb[1];
    #pragma unroll
    for (int w=0;w<8;w++){ s0 += rbuf[2*w]; s1 += rbuf[2*w+1]; }
    out[2*b]   = 1.f/(1.f + __expf(-s0));
    out[2*b+1] = 1.f/(1.f + __expf(-s1));
  }
}

// ---------------------------------------------------------------------------
extern "C" void kernel_launch(void* const* d_in, const int* in_sizes, int n_in,
                              void* d_out, int out_size, void* d_ws, size_t ws_size,
                              hipStream_t stream) {
  const float* x  = (const float*)d_in[0];   // [64,2048,256]
  const float* Ww = (const float*)d_in[1];   // [256,512]
  const float* Wb = (const float*)d_in[2];   // [512]
  const float* Uw = (const float*)d_in[3];   // [512,512]
  const float* Ub = (const float*)d_in[4];   // [512]
  const float* Vw = (const float*)d_in[5];   // [512,2]
  const float* Vb = (const float*)d_in[6];   // [2]
  float* out = (float*)d_out;                // [64,2]

  char* ws = (char*)d_ws;
  _Float16* wxh = (_Float16*)ws;                               // 134,217,728 B
  size_t off = 134217728;
  unsigned* Wp  = (unsigned*)(ws + off); off += 262144;
  uint4*    UrP = (uint4*)   (ws + off); off += (size_t)NRP*512*16;
  uint4*    UtL = (uint4*)   (ws + off); off += (size_t)NTL*512*16;
  uint4*    UtG = (uint4*)   (ws + off);

  prep_pack<<<256, 256, 0, stream>>>(Ww, Uw, Wp, UrP, UtL, UtG);
  gemm_wx  <<<4096, 256, 0, stream>>>(x, Wp, Wb, wxh);
  rnn_scan <<<64, 512, 0, stream>>>(UrP, UtL, UtG, wxh, Ub, Vw, Vb, out);
}